// Round 1
// baseline (125397.021 us; speedup 1.0000x reference)
//
#include <hip/hip_runtime.h>
#include <cstddef>

// SparseRNN dilated RNN, 512 sequential steps — persistent-kernel version.
// R2 theory: 57us/step was dominated by 1026 serialized dispatches + a
// latency-bound OUT GEMM (unroll-4 scalar Wo loads => ~128 L2-latency rounds)
// + a half-width reduce kernel. This version runs ONE kernel for all steps:
//   phase A (GEMM partials, same tasks as before, 1 task/block) -> grid barrier
//   phase B (z-reduce+tanh over 65536 threads)                  -> grid barrier
// Grid barrier: 64 spread arrival counters -> super counter -> 8 replicated
// generation lines; __threadfence() provides cross-XCD release (wbl2) /
// acquire (inv). Monotonic counters, memset-reset per launch, timeout+dead
// flag so a residency failure shows as wrong results, not a hang.
// Residency: 1408 blocks x 128thr, LDS 16.9KB, launch_bounds(128,3) caps
// VGPR<=168 => >=6 blocks/CU capacity (1536 >= 1408).

namespace {
constexpr int BB  = 64;    // batch
constexpr int SS  = 512;   // seq len
constexpr int HH  = 512;   // hidden = emb dim
constexpr int NCL = 1000;  // classes
constexpr int RA  = 256;   // activation ring slots (pow2; writes barrier-separated from o<=256 reads)
constexpr int SLOT = BB * HH;        // 32768 floats per time slot
constexpr int NKC = 40;              // K-chunks of 128 per layer (K=5120)
constexpr int GEMMB = NKC * 16;      // 640 tasks/layer (16 n-tiles of 32)
constexpr int OUTB  = 126;           // 63 n-tiles of 16 x 2 m-halves
constexpr int NTASK = 2 * GEMMB + OUTB;  // 1406
constexpr int NBLK  = 1408;          // 64*22: one A-task per block
constexpr int LDST  = 66;            // LDS stride: b64-aligned reads, low conflict
// barrier layout (uint indices into bar):
constexpr int NCTR  = 64;            // arrival counters, 128B apart
constexpr unsigned QUOTA = NBLK / NCTR;  // 22 arrivals per counter line
constexpr int SUPER_OFF = NCTR * 32;     // 2048
constexpr int GEN_OFF   = SUPER_OFF + 32; // 2080 (+ i*32, i<8)
constexpr int DEAD_OFF  = GEN_OFF + 8 * 32; // 2336
}

__device__ __forceinline__ float tanh_f(float x) {
  x = fminf(15.f, fmaxf(-15.f, x));
  float e = __expf(2.f * x);
  return __fdividef(e - 1.f, e + 1.f);
}

__device__ __forceinline__ void gridbar(unsigned* __restrict__ bar,
                                        unsigned epoch, int* sdead) {
  __syncthreads();
  if (threadIdx.x == 0) {
    __threadfence();  // release: flush this XCD's dirty L2 (partials / z) to LLC
    const int g = blockIdx.x & (NCTR - 1);
    unsigned old = __hip_atomic_fetch_add(&bar[g << 5], 1u,
                        __ATOMIC_RELAXED, __HIP_MEMORY_SCOPE_AGENT);
    if (old == QUOTA * epoch - 1u) {
      // last arrival on this counter line -> promote to super counter
      unsigned so = __hip_atomic_fetch_add(&bar[SUPER_OFF], 1u,
                        __ATOMIC_RELAXED, __HIP_MEMORY_SCOPE_AGENT);
      if (so == (unsigned)NCTR * epoch - 1u) {
        // publisher: everyone has arrived (and release-fenced). Broadcast.
        __threadfence();
#pragma unroll
        for (int i = 0; i < 8; ++i)
          __hip_atomic_store(&bar[GEN_OFF + (i << 5)], epoch,
                             __ATOMIC_RELAXED, __HIP_MEMORY_SCOPE_AGENT);
      }
    }
    {
      unsigned it = 0;
      unsigned* genp = &bar[GEN_OFF + ((blockIdx.x & 7) << 5)];
      while (__hip_atomic_load(genp, __ATOMIC_RELAXED,
                               __HIP_MEMORY_SCOPE_AGENT) < epoch) {
        if (++it > 2000000u) {  // ~1s: catastrophic only (residency bug)
          __hip_atomic_store(&bar[DEAD_OFF], 1u,
                             __ATOMIC_RELAXED, __HIP_MEMORY_SCOPE_AGENT);
          break;
        }
        __builtin_amdgcn_s_sleep(8);
      }
    }
    *sdead = (int)__hip_atomic_load(&bar[DEAD_OFF], __ATOMIC_RELAXED,
                                    __HIP_MEMORY_SCOPE_AGENT);
    __threadfence();  // acquire: invalidate stale L1/L2 before reading others' data
  }
  __syncthreads();
}

__global__ __launch_bounds__(128, 3) void rnn_persist(
    const int* __restrict__ x, const float* __restrict__ emb,
    const float* __restrict__ W1, const float* __restrict__ b1v,
    const float* __restrict__ W2, const float* __restrict__ b2v,
    const float* __restrict__ Wo, const float* __restrict__ bo,
    float* __restrict__ pre1p, float* __restrict__ pre2p,
    float* __restrict__ z1a, float* __restrict__ z2a,
    unsigned* __restrict__ bar, float* __restrict__ out)
{
  __shared__ float lds[64 * LDST];  // A tile transposed [k][m]
  __shared__ int sdead;
  const int tid = threadIdx.x;
  const int bid = blockIdx.x;
  unsigned epoch = 0;

  for (int t = 0; t < SS + 2; ++t) {
    // ---------------- Phase A: K-split GEMM partials + OUT ----------------
    for (int task = bid; task < NTASK; task += NBLK) {
      if (task < 2 * GEMMB) {
        // L1/L2 K-split GEMM: 64m x 32n tile, K-chunk 128
        const int layer = (task >= GEMMB) ? 1 : 0;
        const int lb = task - layer * GEMMB;
        const int kcid = lb >> 4;          // 0..39
        const int nb = lb & 15;            // 0..15
        const int u = t - layer;           // step being computed
        if (u < 0 || u >= SS) continue;
        const int sb = kcid >> 2;          // source block 0..9
        const int koff = (kcid & 3) * 128; // col offset in source block
        const float* __restrict__ W = layer ? W2 : W1;
        const float* src = nullptr;
        bool embmode = false;
        if (sb == 0) {
          if (!layer) embmode = true;      // emb gather
          else        src = z1a + (size_t)(u & (RA - 1)) * SLOT;  // z1[t-1]
        } else {
          const int o = 1 << (9 - sb);     // offset 256..1
          if (o > u) continue;             // invalid -> partial skipped in B
          src = (layer ? z2a : z1a) + (size_t)((u - o) & (RA - 1)) * SLOT;
        }
        const int n0 = nb * 32;
        const int mt = tid & 15;           // 4 m-rows each
        const int nt = tid >> 4;           // 0..7, 4 n-cols each
        const int srow = tid >> 4;         // staging row 0..7
        const int sc4 = (tid & 15) * 4;    // staging col*4
        float acc[4][4] = {};
        for (int sc = 0; sc < 128; sc += 64) {
#pragma unroll
          for (int q = 0; q < 8; q++) {
            const int m = q * 8 + srow;
            const int col = koff + sc + sc4;
            float4 v;
            if (embmode) {
              const int xi = x[m * SS + t];
              v = *(const float4*)(emb + (size_t)xi * HH + col);
            } else {
              v = *(const float4*)(src + (size_t)m * HH + col);
            }
            lds[(sc4 + 0) * LDST + m] = v.x;
            lds[(sc4 + 1) * LDST + m] = v.y;
            lds[(sc4 + 2) * LDST + m] = v.z;
            lds[(sc4 + 3) * LDST + m] = v.w;
          }
          __syncthreads();
          const float* __restrict__ Wp =
              W + (size_t)(sb * HH + koff + sc) * HH + n0 + 4 * nt;
#pragma unroll 4
          for (int k = 0; k < 64; k++) {
            float a0 = lds[k * LDST + 4 * mt + 0];
            float a1 = lds[k * LDST + 4 * mt + 1];
            float a2 = lds[k * LDST + 4 * mt + 2];
            float a3 = lds[k * LDST + 4 * mt + 3];
            const float4 w = *(const float4*)(Wp + (size_t)k * HH);
            acc[0][0] = fmaf(a0, w.x, acc[0][0]); acc[0][1] = fmaf(a0, w.y, acc[0][1]);
            acc[0][2] = fmaf(a0, w.z, acc[0][2]); acc[0][3] = fmaf(a0, w.w, acc[0][3]);
            acc[1][0] = fmaf(a1, w.x, acc[1][0]); acc[1][1] = fmaf(a1, w.y, acc[1][1]);
            acc[1][2] = fmaf(a1, w.z, acc[1][2]); acc[1][3] = fmaf(a1, w.w, acc[1][3]);
            acc[2][0] = fmaf(a2, w.x, acc[2][0]); acc[2][1] = fmaf(a2, w.y, acc[2][1]);
            acc[2][2] = fmaf(a2, w.z, acc[2][2]); acc[2][3] = fmaf(a2, w.w, acc[2][3]);
            acc[3][0] = fmaf(a3, w.x, acc[3][0]); acc[3][1] = fmaf(a3, w.y, acc[3][1]);
            acc[3][2] = fmaf(a3, w.z, acc[3][2]); acc[3][3] = fmaf(a3, w.w, acc[3][3]);
          }
          __syncthreads();
        }
        float* pp = (layer ? pre2p : pre1p) + (size_t)kcid * SLOT;
#pragma unroll
        for (int i = 0; i < 4; i++) {
          float4 st = make_float4(acc[i][0], acc[i][1], acc[i][2], acc[i][3]);
          *(float4*)(pp + (size_t)(4 * mt + i) * HH + n0 + 4 * nt) = st;
        }
      } else {
        // OUT GEMM: out[:, t-2, :] = z2a[t-2] @ Wo + bo ; 32m x 16n, K=512
        const int v = t - 2;
        if (v < 0 || v >= SS) continue;
        const int ob = task - 2 * GEMMB;
        const int nb = ob >> 1;
        const int mh = ob & 1;
        const int n0 = nb * 16;
        const float* src = z2a + (size_t)(v & (RA - 1)) * SLOT;
        const int mt = tid & 7;            // 4 rows each (32 rows)
        const int nt = tid >> 3;           // 0..15, 1 col each
        const int srow = tid >> 4;         // 0..7
        const int sc4 = (tid & 15) * 4;
        const int n = n0 + nt;
        const int nn = (n < NCL) ? n : (NCL - 1);  // clamp loads for last tile
        float acc[4] = {};
        for (int sc = 0; sc < HH; sc += 64) {
#pragma unroll
          for (int q = 0; q < 4; q++) {
            const int m = q * 8 + srow;    // local 0..31
            const float4 vv =
                *(const float4*)(src + (size_t)(mh * 32 + m) * HH + sc + sc4);
            lds[(sc4 + 0) * LDST + m] = vv.x;
            lds[(sc4 + 1) * LDST + m] = vv.y;
            lds[(sc4 + 2) * LDST + m] = vv.z;
            lds[(sc4 + 3) * LDST + m] = vv.w;
          }
          __syncthreads();
#pragma unroll 16
          for (int k = 0; k < 64; k++) {
            const float w = Wo[(size_t)(sc + k) * NCL + nn];
            acc[0] = fmaf(lds[k * LDST + 4 * mt + 0], w, acc[0]);
            acc[1] = fmaf(lds[k * LDST + 4 * mt + 1], w, acc[1]);
            acc[2] = fmaf(lds[k * LDST + 4 * mt + 2], w, acc[2]);
            acc[3] = fmaf(lds[k * LDST + 4 * mt + 3], w, acc[3]);
          }
          __syncthreads();
        }
        if (n < NCL) {
#pragma unroll
          for (int i = 0; i < 4; i++) {
            const int m = mh * 32 + 4 * mt + i;
            out[(size_t)m * (SS * NCL) + (size_t)v * NCL + n] = acc[i] + bo[n];
          }
        }
      }
    }

    gridbar(bar, ++epoch, &sdead);
    if (sdead) return;

    // ---------------- Phase B: reduce 40 partials + bias + tanh ----------------
    {
      const int gid = bid * 128 + tid;
      if (gid < 2 * SLOT) {
        const int layer = gid >> 15;
        const int u = t - layer;
        if (u >= 0 && u < SS) {
          const int e = gid & (SLOT - 1);
          const float* __restrict__ pp = layer ? pre2p : pre1p;
          float s = 0.f;
          for (int sb = 0; sb < 10; ++sb) {
            if (sb > 0 && ((1 << (9 - sb)) > u)) continue;  // invalid offset
#pragma unroll
            for (int ks = 0; ks < 4; ++ks)
              s += pp[(size_t)(sb * 4 + ks) * SLOT + e];
          }
          const float* __restrict__ bias = layer ? b2v : b1v;
          const float r = tanh_f(s + bias[e & (HH - 1)]);
          float* za = (layer ? z2a : z1a) + (size_t)(u & (RA - 1)) * SLOT;
          za[e] = r;
        }
      }
    }

    gridbar(bar, ++epoch, &sdead);
    if (sdead) return;
  }
}

extern "C" void kernel_launch(void* const* d_in, const int* in_sizes, int n_in,
                              void* d_out, int out_size, void* d_ws, size_t ws_size,
                              hipStream_t stream) {
  const int*   x   = (const int*)d_in[0];
  const float* emb = (const float*)d_in[1];
  const float* W1  = (const float*)d_in[2];
  const float* b1  = (const float*)d_in[3];
  const float* W2  = (const float*)d_in[4];
  const float* b2  = (const float*)d_in[5];
  const float* Wo  = (const float*)d_in[6];
  const float* bo  = (const float*)d_in[7];
  float* out = (float*)d_out;

  // ws (floats): pre1p[40][64][512] | pre2p[40][64][512] |
  //              z1a[256][64][512]  | z2a[256][64][512]  | barrier (16KB)
  //            = 77.6 MB (< previous 78.64 MB footprint)
  float* pre1p = (float*)d_ws;
  float* pre2p = pre1p + (size_t)NKC * SLOT;
  float* z1a   = pre2p + (size_t)NKC * SLOT;
  float* z2a   = z1a + (size_t)RA * SLOT;
  unsigned* bar = (unsigned*)(z2a + (size_t)RA * SLOT);

  hipMemsetAsync(bar, 0, 16384, stream);  // reset barrier state each run
  hipLaunchKernelGGL(rnn_persist, dim3(NBLK), dim3(128), 0, stream,
                     x, emb, W1, b1, W2, b2, Wo, bo,
                     pre1p, pre2p, z1a, z2a, bar, out);
}

// Round 6
// 79498.816 us; speedup vs baseline: 1.5773x; 1.5773x over previous
//
#include <hip/hip_runtime.h>
#include <cstddef>

// SparseRNN dilated RNN, 512 sequential steps — persistent kernel, fenceless
// grid barrier, ALL cross-block data through compiler-emitted AGENT atomics.
// History:
//  R2 (fence): correct but 122us/barrier — wbl2/inv storms + weight eviction.
//  R4-R6 (hand sc0sc1 asm): failed ~5.7e-2, identical across asm restructures
//    => the sc-flag semantics I assumed (always bypass stale L1/L2) are wrong
//    somewhere; untrustworthy primitive.
//  R7: data path = __hip_atomic_load/store (RELAXED, AGENT scope, 64-bit).
//    Agent atomicity forces resolution at the device coherence point — the
//    same proven-coherent primitive the barrier counters use. No data asm.
// Release: every lane s_waitcnt vmcnt(0) (drains atomic stores) before the
// block's arrival is counted. Acquire: in-order wave issue after gen-poll;
// all subsequent data reads are coherence-point atomics (no stale caches).
// Weights/emb/x stay plain cached loads: L2-resident across all 512 steps.
// Barrier: 64 spread counters -> super counter -> 8 replicated gen lines,
// relaxed agent atomics, timeout+dead flag (fails loudly, never hangs).

namespace {
constexpr int BB  = 64;    // batch
constexpr int SS  = 512;   // seq len
constexpr int HH  = 512;   // hidden = emb dim
constexpr int NCL = 1000;  // classes
constexpr int RA  = 256;   // activation ring slots (pow2; barrier separates
                           // the o==256 read (phase A) from the overwrite (phase B))
constexpr int SLOT = BB * HH;        // 32768 floats per time slot
constexpr int NKC = 40;              // K-chunks of 128 per layer (K=5120)
constexpr int GEMMB = NKC * 16;      // 640 tasks/layer (16 n-tiles of 32)
constexpr int OUTB  = 126;           // 63 n-tiles of 16 x 2 m-halves
constexpr int NTASK = 2 * GEMMB + OUTB;  // 1406
constexpr int NBLK  = 1408;          // one A-task per block; <=6 blocks/CU resident
constexpr int LDST  = 66;            // LDS stride: b64-aligned reads, low conflict
// barrier layout (uint indices into bar):
constexpr int NCTR  = 64;            // arrival counters, 128B apart
constexpr unsigned QUOTA = NBLK / NCTR;  // 22 arrivals per counter line
constexpr int SUPER_OFF = NCTR * 32;     // 2048
constexpr int GEN_OFF   = SUPER_OFF + 32; // 2080 (+ i*32, i<8)
constexpr int DEAD_OFF  = GEN_OFF + 8 * 32; // 2336
}

__device__ __forceinline__ float tanh_f(float x) {
  x = fminf(15.f, fmaxf(-15.f, x));
  float e = __expf(2.f * x);
  return __fdividef(e - 1.f, e + 1.f);
}

// ---- coherent cross-block data access: 64-bit relaxed AGENT atomics ----
// (agent-scope atomicity => resolves at device coherence point; no stale
//  L1/L2 can be observed; compiler emits the correct cache-op sequence)
__device__ __forceinline__ void ld2cg(const float* p, float& a, float& b) {
  unsigned long long v = __hip_atomic_load(
      (const unsigned long long*)p, __ATOMIC_RELAXED, __HIP_MEMORY_SCOPE_AGENT);
  union { unsigned long long u; float f[2]; } c; c.u = v;
  a = c.f[0]; b = c.f[1];
}
__device__ __forceinline__ void st2cg(float* p, float a, float b) {
  union { unsigned long long u; float f[2]; } c; c.f[0] = a; c.f[1] = b;
  __hip_atomic_store((unsigned long long*)p, c.u,
                     __ATOMIC_RELAXED, __HIP_MEMORY_SCOPE_AGENT);
}
__device__ __forceinline__ void waitvm0() {
  asm volatile("s_waitcnt vmcnt(0)" ::: "memory");
}

__device__ __forceinline__ void gridbar(unsigned* __restrict__ bar,
                                        unsigned epoch, int* sdead) {
  waitvm0();        // RELEASE, per-lane: all atomic data stores are at the
                    // coherence point before this block's arrival is counted.
  __syncthreads();
  if (threadIdx.x == 0) {
    const int g = blockIdx.x & (NCTR - 1);
    unsigned old = __hip_atomic_fetch_add(&bar[g << 5], 1u,
                        __ATOMIC_RELAXED, __HIP_MEMORY_SCOPE_AGENT);
    if (old == QUOTA * epoch - 1u) {
      unsigned so = __hip_atomic_fetch_add(&bar[SUPER_OFF], 1u,
                        __ATOMIC_RELAXED, __HIP_MEMORY_SCOPE_AGENT);
      if (so == (unsigned)NCTR * epoch - 1u) {
#pragma unroll
        for (int i = 0; i < 8; ++i)
          __hip_atomic_store(&bar[GEN_OFF + (i << 5)], epoch,
                             __ATOMIC_RELAXED, __HIP_MEMORY_SCOPE_AGENT);
      }
    }
    {
      unsigned it = 0;
      unsigned* genp = &bar[GEN_OFF + ((blockIdx.x & 7) << 5)];
      while (__hip_atomic_load(genp, __ATOMIC_RELAXED,
                               __HIP_MEMORY_SCOPE_AGENT) < epoch) {
        if (++it > 4000000u) {  // catastrophic only (residency bug)
          __hip_atomic_store(&bar[DEAD_OFF], 1u,
                             __ATOMIC_RELAXED, __HIP_MEMORY_SCOPE_AGENT);
          break;
        }
        __builtin_amdgcn_s_sleep(8);
      }
    }
    *sdead = (int)__hip_atomic_load(&bar[DEAD_OFF], __ATOMIC_RELAXED,
                                    __HIP_MEMORY_SCOPE_AGENT);
  }
  __syncthreads();
}

__global__ __launch_bounds__(128, 3) void rnn_persist(
    const int* __restrict__ x, const float* __restrict__ emb,
    const float* __restrict__ W1, const float* __restrict__ b1v,
    const float* __restrict__ W2, const float* __restrict__ b2v,
    const float* __restrict__ Wo, const float* __restrict__ bo,
    float* __restrict__ pre1p, float* __restrict__ pre2p,
    float* __restrict__ z1a, float* __restrict__ z2a,
    unsigned* __restrict__ bar, float* __restrict__ out)
{
  __shared__ float lds[64 * LDST];  // A tile transposed [k][m]
  __shared__ int sdead;
  const int tid = threadIdx.x;
  const int bid = blockIdx.x;
  unsigned epoch = 0;

  for (int t = 0; t < SS + 2; ++t) {
    // ---------------- Phase A: K-split GEMM partials + OUT ----------------
    for (int task = bid; task < NTASK; task += NBLK) {
      if (task < 2 * GEMMB) {
        // L1/L2 K-split GEMM: 64m x 32n tile, K-chunk 128
        const int layer = (task >= GEMMB) ? 1 : 0;
        const int lb = task - layer * GEMMB;
        const int kcid = lb >> 4;          // 0..39
        const int nb = lb & 15;            // 0..15
        const int u = t - layer;           // step being computed
        if (u < 0 || u >= SS) continue;
        const int sb = kcid >> 2;          // source block 0..9
        const int koff = (kcid & 3) * 128; // col offset in source block
        const float* __restrict__ W = layer ? W2 : W1;
        const float* src = nullptr;
        bool embmode = false;
        if (sb == 0) {
          if (!layer) embmode = true;      // emb gather (read-only, L2-cached)
          else        src = z1a + (size_t)(u & (RA - 1)) * SLOT;  // z1[t-1]
        } else {
          const int o = 1 << (9 - sb);     // offset 256..1
          if (o > u) continue;             // invalid -> partial skipped in B
          src = (layer ? z2a : z1a) + (size_t)((u - o) & (RA - 1)) * SLOT;
        }
        const int n0 = nb * 32;
        const int mt = tid & 15;           // 4 m-rows each
        const int nt = tid >> 4;           // 0..7, 4 n-cols each
        const int srow = tid >> 4;         // staging row 0..7
        const int sc4 = (tid & 15) * 4;    // staging col*4
        float acc[4][4] = {};
        for (int sc = 0; sc < 128; sc += 64) {
          const int col = koff + sc + sc4;
          if (embmode) {
#pragma unroll
            for (int q = 0; q < 8; q++) {
              const int m = q * 8 + srow;
              const int xi = x[m * SS + t];
              const float4 v = *(const float4*)(emb + (size_t)xi * HH + col);
              lds[(sc4 + 0) * LDST + m] = v.x;
              lds[(sc4 + 1) * LDST + m] = v.y;
              lds[(sc4 + 2) * LDST + m] = v.z;
              lds[(sc4 + 3) * LDST + m] = v.w;
            }
          } else {
#pragma unroll
            for (int q = 0; q < 8; q++) {
              const int m = q * 8 + srow;
              const float* p = src + (size_t)m * HH + col;
              float a, b, c, d;
              ld2cg(p, a, b); ld2cg(p + 2, c, d);
              lds[(sc4 + 0) * LDST + m] = a;
              lds[(sc4 + 1) * LDST + m] = b;
              lds[(sc4 + 2) * LDST + m] = c;
              lds[(sc4 + 3) * LDST + m] = d;
            }
          }
          __syncthreads();
          const float* __restrict__ Wp =
              W + (size_t)(sb * HH + koff + sc) * HH + n0 + 4 * nt;
#pragma unroll 4
          for (int k = 0; k < 64; k++) {
            float a0 = lds[k * LDST + 4 * mt + 0];
            float a1 = lds[k * LDST + 4 * mt + 1];
            float a2 = lds[k * LDST + 4 * mt + 2];
            float a3 = lds[k * LDST + 4 * mt + 3];
            const float4 w = *(const float4*)(Wp + (size_t)k * HH);
            acc[0][0] = fmaf(a0, w.x, acc[0][0]); acc[0][1] = fmaf(a0, w.y, acc[0][1]);
            acc[0][2] = fmaf(a0, w.z, acc[0][2]); acc[0][3] = fmaf(a0, w.w, acc[0][3]);
            acc[1][0] = fmaf(a1, w.x, acc[1][0]); acc[1][1] = fmaf(a1, w.y, acc[1][1]);
            acc[1][2] = fmaf(a1, w.z, acc[1][2]); acc[1][3] = fmaf(a1, w.w, acc[1][3]);
            acc[2][0] = fmaf(a2, w.x, acc[2][0]); acc[2][1] = fmaf(a2, w.y, acc[2][1]);
            acc[2][2] = fmaf(a2, w.z, acc[2][2]); acc[2][3] = fmaf(a2, w.w, acc[2][3]);
            acc[3][0] = fmaf(a3, w.x, acc[3][0]); acc[3][1] = fmaf(a3, w.y, acc[3][1]);
            acc[3][2] = fmaf(a3, w.z, acc[3][2]); acc[3][3] = fmaf(a3, w.w, acc[3][3]);
          }
          __syncthreads();
        }
        float* pp = (layer ? pre2p : pre1p) + (size_t)kcid * SLOT;
#pragma unroll
        for (int i = 0; i < 4; i++) {
          float* p = pp + (size_t)(4 * mt + i) * HH + n0 + 4 * nt;
          st2cg(p, acc[i][0], acc[i][1]);
          st2cg(p + 2, acc[i][2], acc[i][3]);
        }
      } else {
        // OUT GEMM: out[:, t-2, :] = z2a[t-2] @ Wo + bo ; 32m x 16n, K=512
        const int v = t - 2;
        if (v < 0 || v >= SS) continue;
        const int ob = task - 2 * GEMMB;
        const int nb = ob >> 1;
        const int mh = ob & 1;
        const int n0 = nb * 16;
        const float* src = z2a + (size_t)(v & (RA - 1)) * SLOT;
        const int mt = tid & 7;            // 4 rows each (32 rows)
        const int nt = tid >> 3;           // 0..15, 1 col each
        const int srow = tid >> 4;         // 0..7
        const int sc4 = (tid & 15) * 4;
        const int n = n0 + nt;
        const int nn = (n < NCL) ? n : (NCL - 1);  // clamp loads for last tile
        float acc[4] = {};
        for (int sc = 0; sc < HH; sc += 64) {
#pragma unroll
          for (int q = 0; q < 4; q++) {
            const int m = q * 8 + srow;    // local 0..31
            const float* p = src + (size_t)(mh * 32 + m) * HH + sc + sc4;
            float a, b, c, d;
            ld2cg(p, a, b); ld2cg(p + 2, c, d);
            lds[(sc4 + 0) * LDST + m] = a;
            lds[(sc4 + 1) * LDST + m] = b;
            lds[(sc4 + 2) * LDST + m] = c;
            lds[(sc4 + 3) * LDST + m] = d;
          }
          __syncthreads();
#pragma unroll 16
          for (int k = 0; k < 64; k++) {
            const float w = Wo[(size_t)(sc + k) * NCL + nn];
            acc[0] = fmaf(lds[k * LDST + 4 * mt + 0], w, acc[0]);
            acc[1] = fmaf(lds[k * LDST + 4 * mt + 1], w, acc[1]);
            acc[2] = fmaf(lds[k * LDST + 4 * mt + 2], w, acc[2]);
            acc[3] = fmaf(lds[k * LDST + 4 * mt + 3], w, acc[3]);
          }
          __syncthreads();
        }
        if (n < NCL) {
#pragma unroll
          for (int i = 0; i < 4; i++) {
            const int m = mh * 32 + 4 * mt + i;
            out[(size_t)m * (SS * NCL) + (size_t)v * NCL + n] = acc[i] + bo[n];
          }
        }
      }
    }

    gridbar(bar, ++epoch, &sdead);
    if (sdead) return;

    // ---------------- Phase B: reduce 40 partials + bias + tanh ----------------
    {
      const int gid = bid * 128 + tid;
      if (gid < 2 * SLOT) {
        const int layer = gid >> 15;
        const int u = t - layer;
        if (u >= 0 && u < SS) {
          const int e = gid & (SLOT - 1);
          const int e4 = e * 4;  // gid covers SLOT/4 elements per layer? no:
          // NOTE: 2*SLOT threads but each thread handles 4 floats => need
          // gid < 2*SLOT/4 mapping. Use e4 = (gid & (SLOT/4 - 1)) * 4.
          (void)e4;
        }
      }
      // Corrected mapping: 2 layers * SLOT/4 thread-slots of 4 floats each.
      if (gid < 2 * (SLOT / 4)) {
        const int layer = gid >= (SLOT / 4) ? 1 : 0;
        const int u = t - layer;
        if (u >= 0 && u < SS) {
          const int e4 = (gid & (SLOT / 4 - 1)) * 4;
          const float* __restrict__ pp = layer ? pre2p : pre1p;
          float s0 = 0.f, s1 = 0.f, s2 = 0.f, s3 = 0.f;
          for (int sb = 0; sb < 10; ++sb) {
            if (sb > 0 && ((1 << (9 - sb)) > u)) continue;  // invalid offset
#pragma unroll
            for (int ks = 0; ks < 4; ++ks) {
              const float* p = pp + (size_t)(sb * 4 + ks) * SLOT + e4;
              float a, b, c, d;
              ld2cg(p, a, b); ld2cg(p + 2, c, d);
              s0 += a; s1 += b; s2 += c; s3 += d;
            }
          }
          const float* __restrict__ bias = layer ? b2v : b1v;
          const int bc = e4 & (HH - 1);
          float* za = (layer ? z2a : z1a) + (size_t)(u & (RA - 1)) * SLOT;
          st2cg(za + e4 + 0, tanh_f(s0 + bias[bc + 0]), tanh_f(s1 + bias[bc + 1]));
          st2cg(za + e4 + 2, tanh_f(s2 + bias[bc + 2]), tanh_f(s3 + bias[bc + 3]));
        }
      }
    }

    gridbar(bar, ++epoch, &sdead);
    if (sdead) return;
  }
}

extern "C" void kernel_launch(void* const* d_in, const int* in_sizes, int n_in,
                              void* d_out, int out_size, void* d_ws, size_t ws_size,
                              hipStream_t stream) {
  const int*   x   = (const int*)d_in[0];
  const float* emb = (const float*)d_in[1];
  const float* W1  = (const float*)d_in[2];
  const float* b1  = (const float*)d_in[3];
  const float* W2  = (const float*)d_in[4];
  const float* b2  = (const float*)d_in[5];
  const float* Wo  = (const float*)d_in[6];
  const float* bo  = (const float*)d_in[7];
  float* out = (float*)d_out;

  // ws (floats): pre1p[40][64][512] | pre2p[40][64][512] |
  //              z1a[256][64][512]  | z2a[256][64][512]  | barrier (16KB)
  float* pre1p = (float*)d_ws;
  float* pre2p = pre1p + (size_t)NKC * SLOT;
  float* z1a   = pre2p + (size_t)NKC * SLOT;
  float* z2a   = z1a + (size_t)RA * SLOT;
  unsigned* bar = (unsigned*)(z2a + (size_t)RA * SLOT);

  (void)hipMemsetAsync(bar, 0, 16384, stream);  // reset barrier state each run
  hipLaunchKernelGGL(rnn_persist, dim3(NBLK), dim3(128), 0, stream,
                     x, emb, W1, b1, W2, b2, Wo, bo,
                     pre1p, pre2p, z1a, z2a, bar, out);
}